// Round 2
// baseline (5221.386 us; speedup 1.0000x reference)
//
#include <hip/hip_runtime.h>
#include <math.h>

// b=16, C=512, H=W=56, wsz=7, X=Y=8, nw=64 windows/img, n=49, tokens=50
// heads=16, dhead=32, INNER=512, total windows bw = 1024
#define SCALE_D 0.17677669529663687f  // 32^-0.5

// ws layout (floats):
//  OUT1 @ 0          size 26,214,400  ([w(1024)*16+h][token(50)*32+d])  [reused: FMAP]
//  G    @ 26,214,400 size 524,288     (16 x 512 x 64)
//  QK   @ 26,738,688 size 1,048,576   (16 x 1024 x 64)
//  total 27,787,264 floats = 111.1 MB
// AGG lives in d_out (25,690,112 floats) — dead before final GEMM overwrites it.

// ---------------- K1: fused gather + QKV projection + stage-1 attention -------------
// one block per (window, head); 256 threads = (rp 0..7) x (cp 0..31)
__global__ __launch_bounds__(256) void k_qkv_attn1(const float* __restrict__ x,
                                                   const float* __restrict__ wtok,
                                                   const float* __restrict__ w_qkv,
                                                   float* __restrict__ OUT1) {
  const int w = blockIdx.x >> 4, h = blockIdx.x & 15;
  const int bb = w >> 6, rem = w & 63, Xw = rem >> 3, Yw = rem & 7;
  const int tid = threadIdx.x;
  const int rp = tid >> 5;   // row group 0..7 (12 rows each of 96)
  const int cp = tid & 31;   // token lane; handles tokens cp and cp+32

  __shared__ __align__(16) float xs[32][64];   // [kk][token], zero-padded i>=50
  __shared__ __align__(16) float wts[96][36];  // [qkvrow][kk], row stride 144B (16-aligned)
  __shared__ float qs[50 * 33], ks[50 * 33], vs[50 * 33];
  __shared__ float sd[50 * 52];
  __shared__ float smx[50], ssum[50];

  float acc[12][2];
#pragma unroll
  for (int j = 0; j < 12; ++j) acc[j][0] = acc[j][1] = 0.f;

  for (int k0 = 0; k0 < 512; k0 += 32) {
    // stage xc chunk [32 k][64 tokens] (token 0 = window token, 1..49 from x, pad 0)
    for (int t = tid; t < 2048; t += 256) {
      int kk = t >> 6, i = t & 63;
      int c = k0 + kk;
      float v = 0.f;
      if (i == 0) {
        v = wtok[c];
      } else if (i < 50) {
        int j = i - 1, r7 = j / 7, c7 = j % 7;
        v = x[((bb * 512 + c) * 56 + Xw * 7 + r7) * 56 + Yw * 7 + c7];
      }
      xs[kk][i] = v;
    }
    // stage 96 weight rows (32 q, 32 k, 32 v for this head) x 32 k
    for (int t = tid; t < 3072; t += 256) {
      int row = t >> 5, kk = t & 31;
      int grow = (row >> 5) * 512 + h * 32 + (row & 31);
      wts[row][kk] = w_qkv[grow * 512 + k0 + kk];
    }
    __syncthreads();
#pragma unroll
    for (int kk4 = 0; kk4 < 8; ++kk4) {
      float4 wv[12];
#pragma unroll
      for (int j = 0; j < 12; ++j) wv[j] = *(const float4*)&wts[rp * 12 + j][kk4 * 4];
#pragma unroll
      for (int q = 0; q < 4; ++q) {
        int kk = kk4 * 4 + q;
        float x0 = xs[kk][cp], x1 = xs[kk][cp + 32];
#pragma unroll
        for (int j = 0; j < 12; ++j) {
          float wq = (q == 0) ? wv[j].x : (q == 1) ? wv[j].y : (q == 2) ? wv[j].z : wv[j].w;
          acc[j][0] += wq * x0;
          acc[j][1] += wq * x1;
        }
      }
    }
    __syncthreads();
  }

  // scatter projections to q/k/v tiles [token][d] (stride 33)
#pragma unroll
  for (int j = 0; j < 12; ++j) {
    int row = rp * 12 + j;
    int sec = row >> 5, dd = row & 31;
    float* dst = (sec == 0) ? qs : (sec == 1) ? ks : vs;
    float sc = (sec == 0) ? SCALE_D : 1.f;
    if (cp < 50) dst[cp * 33 + dd] = acc[j][0] * sc;
    if (cp + 32 < 50) dst[(cp + 32) * 33 + dd] = acc[j][1] * sc;
  }
  __syncthreads();

  // scores
  for (int t = tid; t < 2500; t += 256) {
    int i = t / 50, j = t % 50;
    float s = 0.f;
#pragma unroll
    for (int dd = 0; dd < 32; ++dd) s += qs[i * 33 + dd] * ks[j * 33 + dd];
    sd[i * 52 + j] = s;
  }
  __syncthreads();
  if (tid < 50) {
    float mx = -1e30f;
    for (int j = 0; j < 50; ++j) mx = fmaxf(mx, sd[tid * 52 + j]);
    float sm = 0.f;
    for (int j = 0; j < 50; ++j) sm += expf(sd[tid * 52 + j] - mx);
    smx[tid] = mx;
    ssum[tid] = 1.f / sm;
  }
  __syncthreads();
  for (int t = tid; t < 2500; t += 256) {
    int i = t / 50, j = t % 50;
    sd[i * 52 + j] = expf(sd[i * 52 + j] - smx[i]) * ssum[i];
  }
  __syncthreads();
  // out = P @ V  -> OUT1[(w*16+h)*1600 + i*32+dd]
  for (int t = tid; t < 1600; t += 256) {
    int i = t >> 5, dd = t & 31;
    float o = 0.f;
#pragma unroll
    for (int j = 0; j < 50; ++j) o += sd[i * 52 + j] * vs[j * 33 + dd];
    OUT1[(long)blockIdx.x * 1600 + t] = o;
  }
}

// ---------------- generic f32 GEMM: C[M][N] = A[M][K] * B[K][N] (+bias[m]) ----------
__global__ __launch_bounds__(256) void k_gemm(const float* __restrict__ A,
                                              const float* __restrict__ Bg,
                                              float* __restrict__ C,
                                              const float* __restrict__ bias,
                                              int M, int N, int K,
                                              long sB, long sC) {
  Bg += (long)blockIdx.z * sB;
  C  += (long)blockIdx.z * sC;
  __shared__ __align__(16) float As[32][132];
  __shared__ __align__(16) float Bs[32][132];
  const int tid = threadIdx.x;
  const int tx = tid & 15, ty = tid >> 4;
  const int m0 = blockIdx.y * 128, n0 = blockIdx.x * 128;

  float acc[8][8];
#pragma unroll
  for (int q = 0; q < 8; ++q)
#pragma unroll
    for (int r = 0; r < 8; ++r) acc[q][r] = 0.f;

  for (int k0 = 0; k0 < K; k0 += 32) {
#pragma unroll
    for (int it = 0; it < 4; ++it) {
      int idx = tid + it * 256;
      int row = idx >> 3, c4 = idx & 7;
      const float4 f = *(const float4*)&A[(long)(m0 + row) * K + k0 + c4 * 4];
      As[c4 * 4 + 0][row] = f.x;
      As[c4 * 4 + 1][row] = f.y;
      As[c4 * 4 + 2][row] = f.z;
      As[c4 * 4 + 3][row] = f.w;
    }
#pragma unroll
    for (int it = 0; it < 4; ++it) {
      int idx = tid + it * 256;
      int row = idx >> 5, c4 = idx & 31;
      int col = n0 + c4 * 4;
      float4 f;
      if (col + 3 < N) {
        f = *(const float4*)&Bg[(long)(k0 + row) * N + col];
      } else {
        f.x = (col + 0 < N) ? Bg[(long)(k0 + row) * N + col + 0] : 0.f;
        f.y = (col + 1 < N) ? Bg[(long)(k0 + row) * N + col + 1] : 0.f;
        f.z = (col + 2 < N) ? Bg[(long)(k0 + row) * N + col + 2] : 0.f;
        f.w = (col + 3 < N) ? Bg[(long)(k0 + row) * N + col + 3] : 0.f;
      }
      *(float4*)&Bs[row][c4 * 4] = f;
    }
    __syncthreads();
#pragma unroll
    for (int kk = 0; kk < 32; ++kk) {
      const float4 a0 = *(const float4*)&As[kk][ty * 8];
      const float4 a1 = *(const float4*)&As[kk][ty * 8 + 4];
      const float4 b0 = *(const float4*)&Bs[kk][tx * 8];
      const float4 b1 = *(const float4*)&Bs[kk][tx * 8 + 4];
      const float am[8] = {a0.x, a0.y, a0.z, a0.w, a1.x, a1.y, a1.z, a1.w};
      const float bn[8] = {b0.x, b0.y, b0.z, b0.w, b1.x, b1.y, b1.z, b1.w};
#pragma unroll
      for (int q = 0; q < 8; ++q)
#pragma unroll
        for (int r = 0; r < 8; ++r) acc[q][r] += am[q] * bn[r];
    }
    __syncthreads();
  }

#pragma unroll
  for (int q = 0; q < 8; ++q) {
    int m = m0 + ty * 8 + q;
    float bv = bias ? bias[m] : 0.f;
#pragma unroll
    for (int half = 0; half < 8; half += 4) {
      int col = n0 + tx * 8 + half;
      if (col + 3 < N) {
        float4 v;
        v.x = acc[q][half + 0] + bv;
        v.y = acc[q][half + 1] + bv;
        v.z = acc[q][half + 2] + bv;
        v.w = acc[q][half + 3] + bv;
        *(float4*)&C[(long)m * N + col] = v;
      } else {
#pragma unroll
        for (int rr = 0; rr < 4; ++rr)
          if (col + rr < N) C[(long)m * N + col + rr] = acc[q][half + rr] + bv;
      }
    }
  }
}

// ---------------- K3: LayerNorm + exact GELU on window tokens ------------------------
__global__ __launch_bounds__(256) void k_ln_gelu(const float* __restrict__ OUT1,
                                                 const float* __restrict__ lnw,
                                                 const float* __restrict__ lnb,
                                                 float* __restrict__ G) {
  const int tid = threadIdx.x;
  const int r = blockIdx.x * 8 + (tid >> 5);  // row = (bb*64+wp)*16+hh
  const int l = tid & 31;
  const int bb = r >> 10, hh = (r >> 6) & 15, wp = r & 63;
  float v = OUT1[((long)((bb * 64 + wp) * 16 + hh)) * 1600 + l];
  float s = v, s2 = v * v;
#pragma unroll
  for (int o = 16; o >= 1; o >>= 1) {
    s += __shfl_xor(s, o, 32);
    s2 += __shfl_xor(s2, o, 32);
  }
  float mu = s * (1.f / 32.f);
  float var = s2 * (1.f / 32.f) - mu * mu;
  float xn = (v - mu) * rsqrtf(var + 1e-5f) * lnw[l] + lnb[l];
  float g = 0.5f * xn * (1.f + erff(xn * 0.70710678118654752f));
  G[((long)(bb * 512 + hh * 32 + l)) * 64 + wp] = g;
}

// ---------------- K5: stage-2 attention + aggregation -------------------------------
__global__ __launch_bounds__(256) void k_attn2_agg(const float* __restrict__ QK,
                                                   const float* __restrict__ OUT1,
                                                   float* __restrict__ AGG) {
  const int bh = blockIdx.x;
  const int bb = bh >> 4, hh = bh & 15;
  const int tid = threadIdx.x;
  __shared__ float wqs[64 * 33], wks[64 * 33];
  __shared__ float sd[64 * 65];
  __shared__ __align__(16) float pt[64 * 68];
  __shared__ float smx[64], ssum[64];

  for (int t = tid; t < 2048; t += 256) {
    int dd = t >> 6, i = t & 63;
    wqs[i * 33 + dd] = QK[((long)(bb * 1024 + hh * 64 + dd)) * 64 + i] * SCALE_D;
    wks[i * 33 + dd] = QK[((long)(bb * 1024 + hh * 64 + 32 + dd)) * 64 + i];
  }
  __syncthreads();
  for (int t = tid; t < 4096; t += 256) {
    int i = t >> 6, j = t & 63;
    float s = 0.f;
#pragma unroll
    for (int dd = 0; dd < 32; ++dd) s += wqs[i * 33 + dd] * wks[j * 33 + dd];
    sd[i * 65 + j] = s;
  }
  __syncthreads();
  if (tid < 64) {
    float mx = -1e30f;
    for (int j = 0; j < 64; ++j) mx = fmaxf(mx, sd[tid * 65 + j]);
    float sm = 0.f;
    for (int j = 0; j < 64; ++j) sm += expf(sd[tid * 65 + j] - mx);
    smx[tid] = mx;
    ssum[tid] = 1.f / sm;
  }
  __syncthreads();
  for (int t = tid; t < 4096; t += 256) {
    int i = t >> 6, j = t & 63;
    pt[j * 68 + i] = expf(sd[i * 65 + j] - smx[i]) * ssum[i];  // transposed P
  }
  __syncthreads();

  const int jd = blockIdx.y * 256 + tid;  // 0..1791, active < 1568
  const bool act = jd < 1568;
  float acc[64];
#pragma unroll
  for (int i = 0; i < 64; ++i) acc[i] = 0.f;
  for (int wp = 0; wp < 64; ++wp) {
    float pv = act ? OUT1[((long)((bb * 64 + wp) * 16 + hh)) * 1600 + 32 + jd] : 0.f;
#pragma unroll
    for (int ii = 0; ii < 64; ii += 4) {
      const float4 p = *(const float4*)&pt[wp * 68 + ii];
      acc[ii + 0] += p.x * pv;
      acc[ii + 1] += p.y * pv;
      acc[ii + 2] += p.z * pv;
      acc[ii + 3] += p.w * pv;
    }
  }
  if (act) {
    long base = (long)bh * 64 * 1568 + jd;
#pragma unroll
    for (int i = 0; i < 64; ++i) AGG[base + (long)i * 1568] = acc[i];
  }
}

// ---------------- K6: AGG (bh,i,j*32+d) -> FMAP (b, h*32+d, H, W) --------------------
__global__ __launch_bounds__(256) void k_fmap(const float* __restrict__ AGG,
                                              float* __restrict__ FMAP) {
  const int idx = blockIdx.x;  // (bb*16+hh)*64 + wp
  const int wp = idx & 63, hh = (idx >> 6) & 15, bb = idx >> 10;
  const int Xw = wp >> 3, Yw = wp & 7;
  __shared__ float s[49 * 33];
  const int tid = threadIdx.x;
  const long abase = (long)((bb * 16 + hh) * 64 + wp) * 1568;
  for (int t = tid; t < 1568; t += 256) s[(t >> 5) * 33 + (t & 31)] = AGG[abase + t];
  __syncthreads();
  for (int t = tid; t < 1568; t += 256) {
    int dd = t / 49, j = t - dd * 49;
    int r7 = j / 7, c7 = j - r7 * 7;
    FMAP[((long)(bb * 512 + hh * 32 + dd)) * 3136 + (Xw * 7 + r7) * 56 + Yw * 7 + c7] =
        s[j * 33 + dd];
  }
}

// ---------------- launch ----------------
extern "C" void kernel_launch(void* const* d_in, const int* in_sizes, int n_in,
                              void* d_out, int out_size, void* d_ws, size_t ws_size,
                              hipStream_t stream) {
  const float* x     = (const float*)d_in[0];
  const float* w_qkv = (const float*)d_in[1];
  const float* wt    = (const float*)d_in[2];
  const float* lnw   = (const float*)d_in[3];
  const float* lnb   = (const float*)d_in[4];
  const float* w_qk  = (const float*)d_in[5];
  const float* b_qk  = (const float*)d_in[6];
  const float* w_out = (const float*)d_in[7];
  const float* b_out = (const float*)d_in[8];
  float* out = (float*)d_out;
  float* ws  = (float*)d_ws;

  float* OUT1 = ws;                  // 26,214,400 floats
  float* G    = ws + 26214400L;      // 524,288 floats
  float* QK   = ws + 26738688L;      // 1,048,576 floats
  float* AGG  = out;                 // 25,690,112 floats (dead before final GEMM)
  float* FMAP = OUT1;                // reuse (OUT1 dead after attn2)

  // 1. fused gather + QKV projection + stage-1 attention
  k_qkv_attn1<<<16384, 256, 0, stream>>>(x, wt, w_qkv, OUT1);
  // 2. LN + GELU on window tokens -> G [b][h*32+d][w']
  k_ln_gelu<<<2048, 256, 0, stream>>>(OUT1, lnw, lnb, G);
  // 3. qk = w_qk(1024x512) @ G[b](512x64) + b_qk
  k_gemm<<<dim3(1, 8, 16), 256, 0, stream>>>(w_qk, G, QK, b_qk,
                                             1024, 64, 512, 512L * 64, 1024L * 64);
  // 4. stage-2 attention + aggregation -> AGG (in d_out)
  k_attn2_agg<<<dim3(256, 7, 1), 256, 0, stream>>>(QK, OUT1, AGG);
  // 5. AGG -> FMAP [b][c][H][W]
  k_fmap<<<16384, 256, 0, stream>>>(AGG, FMAP);
  // 6. out = w_out(512x512) @ FMAP[b](512x3136) + b_out
  k_gemm<<<dim3(25, 4, 16), 256, 0, stream>>>(w_out, FMAP, out, b_out,
                                              512, 3136, 512, 512L * 3136, 512L * 3136);
}

// Round 3
// 2484.776 us; speedup vs baseline: 2.1014x; 2.1014x over previous
//
#include <hip/hip_runtime.h>
#include <math.h>

// b=16, C=512, H=W=56, wsz=7, X=Y=8, nw=64 windows/img, n=49, tokens=50
// heads=16, dhead=32, INNER=512
#define SCALE_D 0.17677669529663687f  // 32^-0.5

// ws layout (floats), total 111.1 MB (proven budget):
//  OUT1 @ 0          size 26,214,400  ([w(1024)*16+h][token(50)*32+d])  [reused: FMAP]
//  G    @ 26,214,400 size 524,288     (16 x 512 x 64)
//  QK   @ 26,738,688 size 1,048,576   (16 x 1024 x 64)
// d_out (25.69M floats) doubles as scratch: QKV chunks (1536x12800 = 19.7M floats),
// then AGG (25.69M floats) — both dead before the final GEMM writes d_out.

// -------- K1: QKV chunk GEMM: C[1536][12800] = w_qkv[1536][512] @ Xc_gathered -------
// one chunk = 256 windows (12800 tokens). B is gathered from x/wtok on the fly.
__global__ __launch_bounds__(256) void k_gemm_qkv(const float* __restrict__ A,
                                                  const float* __restrict__ x,
                                                  const float* __restrict__ wtok,
                                                  float* __restrict__ C, int w0) {
  __shared__ __align__(16) float As[32][132];
  __shared__ __align__(16) float Bs[32][132];
  const int tid = threadIdx.x;
  const int tx = tid & 15, ty = tid >> 4;
  const int m0 = blockIdx.y * 128, n0 = blockIdx.x * 128;

  // per-column gather descriptors (fixed across k): offset into x with c-term removed,
  // or -1 for the window-token column.
  int bo[16];
#pragma unroll
  for (int it = 0; it < 2; ++it) {
    int idx = tid + it * 256;
    int c8 = idx & 15;
#pragma unroll
    for (int jj = 0; jj < 8; ++jj) {
      int tt = n0 + c8 * 8 + jj;          // local token id in chunk
      int wl = tt / 50, i = tt % 50;
      int w = w0 + wl;
      int bbw = w >> 6, rem = w & 63, Xw = rem >> 3, Yw = rem & 7;
      bo[it * 8 + jj] = (i == 0) ? -1
          : bbw * 512 * 3136 + (Xw * 7 + (i - 1) / 7) * 56 + Yw * 7 + (i - 1) % 7;
    }
  }

  float acc[8][8];
#pragma unroll
  for (int q = 0; q < 8; ++q)
#pragma unroll
    for (int r = 0; r < 8; ++r) acc[q][r] = 0.f;

  for (int k0 = 0; k0 < 512; k0 += 32) {
    // A tile 128x32 -> As[k][m]
#pragma unroll
    for (int it = 0; it < 4; ++it) {
      int idx = tid + it * 256;
      int row = idx >> 3, c4 = idx & 7;
      const float4 f = *(const float4*)&A[(long)(m0 + row) * 512 + k0 + c4 * 4];
      As[c4 * 4 + 0][row] = f.x;
      As[c4 * 4 + 1][row] = f.y;
      As[c4 * 4 + 2][row] = f.z;
      As[c4 * 4 + 3][row] = f.w;
    }
    // B tile 32x128 gathered from x / wtok
#pragma unroll
    for (int it = 0; it < 2; ++it) {
      int idx = tid + it * 256;
      int row = idx >> 4, c8 = idx & 15;
      int c = k0 + row;
      float wv = wtok[c];
#pragma unroll
      for (int jj = 0; jj < 8; ++jj) {
        int b = bo[it * 8 + jj];
        Bs[row][c8 * 8 + jj] = (b < 0) ? wv : x[b + c * 3136];
      }
    }
    __syncthreads();
#pragma unroll
    for (int kk = 0; kk < 32; ++kk) {
      const float4 a0 = *(const float4*)&As[kk][ty * 8];
      const float4 a1 = *(const float4*)&As[kk][ty * 8 + 4];
      const float4 b0 = *(const float4*)&Bs[kk][tx * 8];
      const float4 b1 = *(const float4*)&Bs[kk][tx * 8 + 4];
      const float am[8] = {a0.x, a0.y, a0.z, a0.w, a1.x, a1.y, a1.z, a1.w};
      const float bn[8] = {b0.x, b0.y, b0.z, b0.w, b1.x, b1.y, b1.z, b1.w};
#pragma unroll
      for (int q = 0; q < 8; ++q)
#pragma unroll
        for (int r = 0; r < 8; ++r) acc[q][r] += am[q] * bn[r];
    }
    __syncthreads();
  }

#pragma unroll
  for (int q = 0; q < 8; ++q) {
    int m = m0 + ty * 8 + q;
#pragma unroll
    for (int half = 0; half < 8; half += 4) {
      int col = n0 + tx * 8 + half;
      float4 v;
      v.x = acc[q][half + 0];
      v.y = acc[q][half + 1];
      v.z = acc[q][half + 2];
      v.w = acc[q][half + 3];
      *(float4*)&C[(long)m * 12800 + col] = v;
    }
  }
}

// ---------------- K2: stage-1 attention over one QKV chunk --------------------------
__global__ __launch_bounds__(256) void k_attn1(const float* __restrict__ QKV,
                                               float* __restrict__ OUT1, int w0) {
  const int wl = blockIdx.x >> 4, h = blockIdx.x & 15;
  __shared__ float qs[50 * 33], ks[50 * 33], vs[50 * 33];
  __shared__ float sd[50 * 52];
  __shared__ float smx[50], ssum[50];
  const int tid = threadIdx.x;

  for (int t = tid; t < 1600; t += 256) {
    int dd = t / 50, i = t % 50;
    long base = (long)(h * 32 + dd) * 12800 + wl * 50 + i;
    qs[i * 33 + dd] = QKV[base] * SCALE_D;
    ks[i * 33 + dd] = QKV[base + 512L * 12800];
    vs[i * 33 + dd] = QKV[base + 1024L * 12800];
  }
  __syncthreads();
  for (int t = tid; t < 2500; t += 256) {
    int i = t / 50, j = t % 50;
    float s = 0.f;
#pragma unroll
    for (int dd = 0; dd < 32; ++dd) s += qs[i * 33 + dd] * ks[j * 33 + dd];
    sd[i * 52 + j] = s;
  }
  __syncthreads();
  if (tid < 50) {
    float mx = -1e30f;
    for (int j = 0; j < 50; ++j) mx = fmaxf(mx, sd[tid * 52 + j]);
    float sm = 0.f;
    for (int j = 0; j < 50; ++j) sm += expf(sd[tid * 52 + j] - mx);
    smx[tid] = mx;
    ssum[tid] = 1.f / sm;
  }
  __syncthreads();
  for (int t = tid; t < 2500; t += 256) {
    int i = t / 50, j = t % 50;
    sd[i * 52 + j] = expf(sd[i * 52 + j] - smx[i]) * ssum[i];
  }
  __syncthreads();
  for (int t = tid; t < 1600; t += 256) {
    int i = t >> 5, dd = t & 31;
    float o = 0.f;
#pragma unroll
    for (int j = 0; j < 50; ++j) o += sd[i * 52 + j] * vs[j * 33 + dd];
    OUT1[((long)((w0 + wl) * 16 + h)) * 1600 + t] = o;
  }
}

// ---------------- generic f32 GEMM: C[M][N] = A[M][K] * B[K][N] (+bias[m]) ----------
__global__ __launch_bounds__(256) void k_gemm(const float* __restrict__ A,
                                              const float* __restrict__ Bg,
                                              float* __restrict__ C,
                                              const float* __restrict__ bias,
                                              int M, int N, int K,
                                              long sB, long sC) {
  Bg += (long)blockIdx.z * sB;
  C  += (long)blockIdx.z * sC;
  __shared__ __align__(16) float As[32][132];
  __shared__ __align__(16) float Bs[32][132];
  const int tid = threadIdx.x;
  const int tx = tid & 15, ty = tid >> 4;
  const int m0 = blockIdx.y * 128, n0 = blockIdx.x * 128;

  float acc[8][8];
#pragma unroll
  for (int q = 0; q < 8; ++q)
#pragma unroll
    for (int r = 0; r < 8; ++r) acc[q][r] = 0.f;

  for (int k0 = 0; k0 < K; k0 += 32) {
#pragma unroll
    for (int it = 0; it < 4; ++it) {
      int idx = tid + it * 256;
      int row = idx >> 3, c4 = idx & 7;
      const float4 f = *(const float4*)&A[(long)(m0 + row) * K + k0 + c4 * 4];
      As[c4 * 4 + 0][row] = f.x;
      As[c4 * 4 + 1][row] = f.y;
      As[c4 * 4 + 2][row] = f.z;
      As[c4 * 4 + 3][row] = f.w;
    }
#pragma unroll
    for (int it = 0; it < 4; ++it) {
      int idx = tid + it * 256;
      int row = idx >> 5, c4 = idx & 31;
      int col = n0 + c4 * 4;
      float4 f;
      if (col + 3 < N) {
        f = *(const float4*)&Bg[(long)(k0 + row) * N + col];
      } else {
        f.x = (col + 0 < N) ? Bg[(long)(k0 + row) * N + col + 0] : 0.f;
        f.y = (col + 1 < N) ? Bg[(long)(k0 + row) * N + col + 1] : 0.f;
        f.z = (col + 2 < N) ? Bg[(long)(k0 + row) * N + col + 2] : 0.f;
        f.w = (col + 3 < N) ? Bg[(long)(k0 + row) * N + col + 3] : 0.f;
      }
      *(float4*)&Bs[row][c4 * 4] = f;
    }
    __syncthreads();
#pragma unroll
    for (int kk = 0; kk < 32; ++kk) {
      const float4 a0 = *(const float4*)&As[kk][ty * 8];
      const float4 a1 = *(const float4*)&As[kk][ty * 8 + 4];
      const float4 b0 = *(const float4*)&Bs[kk][tx * 8];
      const float4 b1 = *(const float4*)&Bs[kk][tx * 8 + 4];
      const float am[8] = {a0.x, a0.y, a0.z, a0.w, a1.x, a1.y, a1.z, a1.w};
      const float bn[8] = {b0.x, b0.y, b0.z, b0.w, b1.x, b1.y, b1.z, b1.w};
#pragma unroll
      for (int q = 0; q < 8; ++q)
#pragma unroll
        for (int r = 0; r < 8; ++r) acc[q][r] += am[q] * bn[r];
    }
    __syncthreads();
  }

#pragma unroll
  for (int q = 0; q < 8; ++q) {
    int m = m0 + ty * 8 + q;
    float bv = bias ? bias[m] : 0.f;
#pragma unroll
    for (int half = 0; half < 8; half += 4) {
      int col = n0 + tx * 8 + half;
      if (col + 3 < N) {
        float4 v;
        v.x = acc[q][half + 0] + bv;
        v.y = acc[q][half + 1] + bv;
        v.z = acc[q][half + 2] + bv;
        v.w = acc[q][half + 3] + bv;
        *(float4*)&C[(long)m * N + col] = v;
      } else {
#pragma unroll
        for (int rr = 0; rr < 4; ++rr)
          if (col + rr < N) C[(long)m * N + col + rr] = acc[q][half + rr] + bv;
      }
    }
  }
}

// ---------------- K3: LayerNorm + exact GELU on window tokens ------------------------
__global__ __launch_bounds__(256) void k_ln_gelu(const float* __restrict__ OUT1,
                                                 const float* __restrict__ lnw,
                                                 const float* __restrict__ lnb,
                                                 float* __restrict__ G) {
  const int tid = threadIdx.x;
  const int r = blockIdx.x * 8 + (tid >> 5);
  const int l = tid & 31;
  const int bb = r >> 10, hh = (r >> 6) & 15, wp = r & 63;
  float v = OUT1[((long)((bb * 64 + wp) * 16 + hh)) * 1600 + l];
  float s = v, s2 = v * v;
#pragma unroll
  for (int o = 16; o >= 1; o >>= 1) {
    s += __shfl_xor(s, o, 32);
    s2 += __shfl_xor(s2, o, 32);
  }
  float mu = s * (1.f / 32.f);
  float var = s2 * (1.f / 32.f) - mu * mu;
  float xn = (v - mu) * rsqrtf(var + 1e-5f) * lnw[l] + lnb[l];
  float g = 0.5f * xn * (1.f + erff(xn * 0.70710678118654752f));
  G[((long)(bb * 512 + hh * 32 + l)) * 64 + wp] = g;
}

// ---------------- K5: stage-2 attention + aggregation -------------------------------
__global__ __launch_bounds__(256) void k_attn2_agg(const float* __restrict__ QK,
                                                   const float* __restrict__ OUT1,
                                                   float* __restrict__ AGG) {
  const int bh = blockIdx.x;
  const int bb = bh >> 4, hh = bh & 15;
  const int tid = threadIdx.x;
  __shared__ float wqs[64 * 33], wks[64 * 33];
  __shared__ float sd[64 * 65];
  __shared__ __align__(16) float pt[64 * 68];
  __shared__ float smx[64], ssum[64];

  for (int t = tid; t < 2048; t += 256) {
    int dd = t >> 6, i = t & 63;
    wqs[i * 33 + dd] = QK[((long)(bb * 1024 + hh * 64 + dd)) * 64 + i] * SCALE_D;
    wks[i * 33 + dd] = QK[((long)(bb * 1024 + hh * 64 + 32 + dd)) * 64 + i];
  }
  __syncthreads();
  for (int t = tid; t < 4096; t += 256) {
    int i = t >> 6, j = t & 63;
    float s = 0.f;
#pragma unroll
    for (int dd = 0; dd < 32; ++dd) s += wqs[i * 33 + dd] * wks[j * 33 + dd];
    sd[i * 65 + j] = s;
  }
  __syncthreads();
  if (tid < 64) {
    float mx = -1e30f;
    for (int j = 0; j < 64; ++j) mx = fmaxf(mx, sd[tid * 65 + j]);
    float sm = 0.f;
    for (int j = 0; j < 64; ++j) sm += expf(sd[tid * 65 + j] - mx);
    smx[tid] = mx;
    ssum[tid] = 1.f / sm;
  }
  __syncthreads();
  for (int t = tid; t < 4096; t += 256) {
    int i = t >> 6, j = t & 63;
    pt[j * 68 + i] = expf(sd[i * 65 + j] - smx[i]) * ssum[i];
  }
  __syncthreads();

  const int jd = blockIdx.y * 256 + tid;
  const bool act = jd < 1568;
  float acc[64];
#pragma unroll
  for (int i = 0; i < 64; ++i) acc[i] = 0.f;
  for (int wp = 0; wp < 64; ++wp) {
    float pv = act ? OUT1[((long)((bb * 64 + wp) * 16 + hh)) * 1600 + 32 + jd] : 0.f;
#pragma unroll
    for (int ii = 0; ii < 64; ii += 4) {
      const float4 p = *(const float4*)&pt[wp * 68 + ii];
      acc[ii + 0] += p.x * pv;
      acc[ii + 1] += p.y * pv;
      acc[ii + 2] += p.z * pv;
      acc[ii + 3] += p.w * pv;
    }
  }
  if (act) {
    long base = (long)bh * 64 * 1568 + jd;
#pragma unroll
    for (int i = 0; i < 64; ++i) AGG[base + (long)i * 1568] = acc[i];
  }
}

// ---------------- K6: AGG (bh,i,j*32+d) -> FMAP (b, h*32+d, H, W) --------------------
__global__ __launch_bounds__(256) void k_fmap(const float* __restrict__ AGG,
                                              float* __restrict__ FMAP) {
  const int idx = blockIdx.x;
  const int wp = idx & 63, hh = (idx >> 6) & 15, bb = idx >> 10;
  const int Xw = wp >> 3, Yw = wp & 7;
  __shared__ float s[49 * 33];
  const int tid = threadIdx.x;
  const long abase = (long)((bb * 16 + hh) * 64 + wp) * 1568;
  for (int t = tid; t < 1568; t += 256) s[(t >> 5) * 33 + (t & 31)] = AGG[abase + t];
  __syncthreads();
  for (int t = tid; t < 1568; t += 256) {
    int dd = t / 49, j = t - dd * 49;
    int r7 = j / 7, c7 = j - r7 * 7;
    FMAP[((long)(bb * 512 + hh * 32 + dd)) * 3136 + (Xw * 7 + r7) * 56 + Yw * 7 + c7] =
        s[j * 33 + dd];
  }
}

// ---------------- launch ----------------
extern "C" void kernel_launch(void* const* d_in, const int* in_sizes, int n_in,
                              void* d_out, int out_size, void* d_ws, size_t ws_size,
                              hipStream_t stream) {
  const float* x     = (const float*)d_in[0];
  const float* w_qkv = (const float*)d_in[1];
  const float* wt    = (const float*)d_in[2];
  const float* lnw   = (const float*)d_in[3];
  const float* lnb   = (const float*)d_in[4];
  const float* w_qk  = (const float*)d_in[5];
  const float* b_qk  = (const float*)d_in[6];
  const float* w_out = (const float*)d_in[7];
  const float* b_out = (const float*)d_in[8];
  float* out = (float*)d_out;
  float* ws  = (float*)d_ws;

  float* OUT1 = ws;                  // 26,214,400 floats
  float* G    = ws + 26214400L;      // 524,288 floats
  float* QK   = ws + 26738688L;      // 1,048,576 floats
  float* QKVc = out;                 // chunk scratch: 19,660,800 floats (fits 25.69M)
  float* AGG  = out;                 // after QKV chunks are dead
  float* FMAP = OUT1;                // after OUT1 is dead

  // 1. QKV projection + stage-1 attention, 4 chunks of 256 windows
  for (int c = 0; c < 4; ++c) {
    k_gemm_qkv<<<dim3(100, 12, 1), 256, 0, stream>>>(w_qkv, x, wt, QKVc, c * 256);
    k_attn1<<<4096, 256, 0, stream>>>(QKVc, OUT1, c * 256);
  }
  // 2. LN + GELU on window tokens -> G [b][h*32+d][w']
  k_ln_gelu<<<2048, 256, 0, stream>>>(OUT1, lnw, lnb, G);
  // 3. qk = w_qk(1024x512) @ G[b](512x64) + b_qk
  k_gemm<<<dim3(1, 8, 16), 256, 0, stream>>>(w_qk, G, QK, b_qk,
                                             1024, 64, 512, 512L * 64, 1024L * 64);
  // 4. stage-2 attention + aggregation -> AGG (in d_out)
  k_attn2_agg<<<dim3(256, 7, 1), 256, 0, stream>>>(QK, OUT1, AGG);
  // 5. AGG -> FMAP [b][c][H][W]
  k_fmap<<<16384, 256, 0, stream>>>(AGG, FMAP);
  // 6. out = w_out(512x512) @ FMAP[b](512x3136) + b_out
  k_gemm<<<dim3(25, 4, 16), 256, 0, stream>>>(w_out, FMAP, out, b_out,
                                              512, 3136, 512, 512L * 3136, 512L * 3136);
}

// Round 4
// 1234.224 us; speedup vs baseline: 4.2305x; 2.0132x over previous
//
#include <hip/hip_runtime.h>
#include <math.h>

// b=16, C=512, H=W=56, wsz=7, X=Y=8, nw=64/img, n=49, tokens=50, heads=16, dhead=32
#define SCALE_D 0.17677669529663687f  // 32^-0.5

typedef __attribute__((ext_vector_type(8))) short short8;
typedef __attribute__((ext_vector_type(4))) float f32x4;

__device__ __forceinline__ unsigned short f2bf(float f) {
  unsigned u = __builtin_bit_cast(unsigned, f);
  unsigned r = u + 0x7FFF + ((u >> 16) & 1);
  return (unsigned short)(r >> 16);
}
__device__ __forceinline__ float bf2f(unsigned short h) {
  unsigned u = ((unsigned)h) << 16;
  return __builtin_bit_cast(float, u);
}
__device__ __forceinline__ void gload16(const void* g, void* l) {
  __builtin_amdgcn_global_load_lds((const __attribute__((address_space(1))) unsigned int*)g,
                                   (__attribute__((address_space(3))) unsigned int*)l,
                                   16, 0, 0);
}

// -------- split f32 -> bf16 hi/lo planes ------------------------------------------
__global__ __launch_bounds__(256) void k_split(const float* __restrict__ src,
                                               unsigned short* __restrict__ hi,
                                               unsigned short* __restrict__ lo, int n) {
  int i = blockIdx.x * 256 + threadIdx.x;
  if (i < n) {
    float v = src[i];
    unsigned short h = f2bf(v);
    hi[i] = h;
    lo[i] = f2bf(v - bf2f(h));
  }
}

// -------- gather Xc^T chunk (2 images) as bf16 hi/lo [6400][512] -------------------
__global__ __launch_bounds__(256) void k_build_xcT(const float* __restrict__ x,
                                                   const float* __restrict__ wtok,
                                                   unsigned short* __restrict__ Thi,
                                                   unsigned short* __restrict__ Tlo,
                                                   int bb0) {
  const int cblk = blockIdx.x;   // 0..7
  const int h    = blockIdx.y;   // 0..55 pixels, 56 = token-0 pass
  const int bbL  = blockIdx.z;   // 0..1
  const int bb   = bb0 + bbL;
  const int tid  = threadIdx.x;
  const int c0   = cblk * 64;
  if (h == 56) {
    for (int e = tid; e < 4096; e += 256) {
      int wl = e >> 6, cl = e & 63;
      float v = wtok[c0 + cl];
      unsigned short hv = f2bf(v);
      long idx = ((long)(bbL * 64 + wl) * 50) * 512 + c0 + cl;
      Thi[idx] = hv;
      Tlo[idx] = f2bf(v - bf2f(hv));
    }
    return;
  }
  __shared__ unsigned short shi[64][57], slo[64][57];
  const int Xw = h / 7, r7 = h % 7;
  for (int e = tid; e < 3584; e += 256) {
    int cl = e / 56, w = e - cl * 56;
    float v = x[((long)(bb * 512 + c0 + cl) * 56 + h) * 56 + w];
    unsigned short hv = f2bf(v);
    shi[cl][w] = hv;
    slo[cl][w] = f2bf(v - bf2f(hv));
  }
  __syncthreads();
  for (int e = tid; e < 3584; e += 256) {
    int row = e >> 6, cl = e & 63;       // row = Yw*7+c7
    int Yw = row / 7, c7 = row - Yw * 7;
    long trow = (long)(bbL * 64 + Xw * 8 + Yw) * 50 + 1 + r7 * 7 + c7;
    Thi[trow * 512 + c0 + cl] = shi[cl][row];
    Tlo[trow * 512 + c0 + cl] = slo[cl][row];
  }
}

// -------- split-bf16 MFMA GEMM: C = A(f32~hi+lo) * B^T(rows=[n][k]) ---------------
// tile 128x128, BK=32, 4 waves (2x2), 16x16x32 bf16 MFMA, 3 passes (hi*hi+hi*lo+lo*hi)
__global__ __launch_bounds__(256, 2) void k_gemm_mfma(
    const unsigned short* __restrict__ Ahi, const unsigned short* __restrict__ Alo,
    const unsigned short* __restrict__ Bhi, const unsigned short* __restrict__ Blo,
    float* __restrict__ C, const float* __restrict__ bias,
    int NC, int brow_stride, long c_stride) {
  __shared__ unsigned short lds[4][128][32];  // Ahi, Alo, Bhi, Blo planes (32 KB)
  const int tid = threadIdx.x;
  const int wv = tid >> 6, lane = tid & 63;
  const int m0 = blockIdx.y * 128, n0 = blockIdx.x * 128;
  const long brow0 = (long)blockIdx.z * brow_stride + n0;
  C += (long)blockIdx.z * c_stride;

  const int wr = wv >> 1, wc = wv & 1;
  const int lr = lane & 15, kb = lane >> 4;
  const int srow = lane >> 2, sju = lane & 3;  // staging: row offset, 16B unit

  f32x4 acc[4][4];
#pragma unroll
  for (int i = 0; i < 4; ++i)
#pragma unroll
    for (int j = 0; j < 4; ++j) {
      f32x4 z = {0.f, 0.f, 0.f, 0.f};
      acc[i][j] = z;
    }

  for (int k0 = 0; k0 < 512; k0 += 32) {
#pragma unroll
    for (int it = 0; it < 2; ++it) {
      const int rloc = (wv * 2 + it) * 16;
      const int r = rloc + srow;
      const long ga = (long)(m0 + r) * 512 + k0 + sju * 8;
      gload16(Ahi + ga, &lds[0][rloc][0]);
      gload16(Alo + ga, &lds[1][rloc][0]);
      const long gb = (brow0 + r) * 512 + k0 + sju * 8;
      gload16(Bhi + gb, &lds[2][rloc][0]);
      gload16(Blo + gb, &lds[3][rloc][0]);
    }
    __syncthreads();
    short8 ah[4], al[4], bh[4], bl[4];
#pragma unroll
    for (int f = 0; f < 4; ++f) {
      int ra = wr * 64 + f * 16 + lr;
      ah[f] = *(const short8*)&lds[0][ra][kb * 8];
      al[f] = *(const short8*)&lds[1][ra][kb * 8];
      int rb = wc * 64 + f * 16 + lr;
      bh[f] = *(const short8*)&lds[2][rb][kb * 8];
      bl[f] = *(const short8*)&lds[3][rb][kb * 8];
    }
#pragma unroll
    for (int i = 0; i < 4; ++i)
#pragma unroll
      for (int j = 0; j < 4; ++j) {
        acc[i][j] = __builtin_amdgcn_mfma_f32_16x16x32_bf16(ah[i], bh[j], acc[i][j], 0, 0, 0);
        acc[i][j] = __builtin_amdgcn_mfma_f32_16x16x32_bf16(ah[i], bl[j], acc[i][j], 0, 0, 0);
        acc[i][j] = __builtin_amdgcn_mfma_f32_16x16x32_bf16(al[i], bh[j], acc[i][j], 0, 0, 0);
      }
    __syncthreads();
  }

#pragma unroll
  for (int i = 0; i < 4; ++i)
#pragma unroll
    for (int nf = 0; nf < 4; ++nf) {
      int col = n0 + wc * 64 + nf * 16 + lr;
      if (col < NC) {
#pragma unroll
        for (int j4 = 0; j4 < 4; ++j4) {
          int row = m0 + wr * 64 + i * 16 + kb * 4 + j4;
          float bv = bias ? bias[row] : 0.f;
          C[(long)row * NC + col] = acc[i][nf][j4] + bv;
        }
      }
    }
}

// -------- stage-1 attention over one QKV chunk (128 windows) -----------------------
__global__ __launch_bounds__(256) void k_attn1(const float* __restrict__ QKV,
                                               float* __restrict__ OUT1, int w0) {
  const int wl = blockIdx.x >> 4, h = blockIdx.x & 15;
  __shared__ float qs[50 * 33], ks[50 * 33], vs[50 * 33];
  __shared__ float sd[50 * 52];
  __shared__ float smx[50], ssum[50];
  const int tid = threadIdx.x;

  for (int t = tid; t < 1600; t += 256) {
    int dd = t / 50, i = t % 50;
    long base = (long)(h * 32 + dd) * 6400 + wl * 50 + i;
    qs[i * 33 + dd] = QKV[base] * SCALE_D;
    ks[i * 33 + dd] = QKV[base + 512L * 6400];
    vs[i * 33 + dd] = QKV[base + 1024L * 6400];
  }
  __syncthreads();
  for (int t = tid; t < 2500; t += 256) {
    int i = t / 50, j = t % 50;
    float s = 0.f;
#pragma unroll
    for (int dd = 0; dd < 32; ++dd) s += qs[i * 33 + dd] * ks[j * 33 + dd];
    sd[i * 52 + j] = s;
  }
  __syncthreads();
  if (tid < 50) {
    float mx = -1e30f;
    for (int j = 0; j < 50; ++j) mx = fmaxf(mx, sd[tid * 52 + j]);
    float sm = 0.f;
    for (int j = 0; j < 50; ++j) sm += expf(sd[tid * 52 + j] - mx);
    smx[tid] = mx;
    ssum[tid] = 1.f / sm;
  }
  __syncthreads();
  for (int t = tid; t < 2500; t += 256) {
    int i = t / 50, j = t % 50;
    sd[i * 52 + j] = expf(sd[i * 52 + j] - smx[i]) * ssum[i];
  }
  __syncthreads();
  for (int t = tid; t < 1600; t += 256) {
    int i = t >> 5, dd = t & 31;
    float o = 0.f;
#pragma unroll
    for (int j = 0; j < 50; ++j) o += sd[i * 52 + j] * vs[j * 33 + dd];
    OUT1[((long)((w0 + wl) * 16 + h)) * 1600 + t] = o;
  }
}

// -------- f32 GEMM (kept for the small qk projection) ------------------------------
__global__ __launch_bounds__(256) void k_gemm(const float* __restrict__ A,
                                              const float* __restrict__ Bg,
                                              float* __restrict__ C,
                                              const float* __restrict__ bias,
                                              int M, int N, int K, long sB, long sC) {
  Bg += (long)blockIdx.z * sB;
  C  += (long)blockIdx.z * sC;
  __shared__ __align__(16) float As[32][132];
  __shared__ __align__(16) float Bs[32][132];
  const int tid = threadIdx.x;
  const int tx = tid & 15, ty = tid >> 4;
  const int m0 = blockIdx.y * 128, n0 = blockIdx.x * 128;

  float acc[8][8];
#pragma unroll
  for (int q = 0; q < 8; ++q)
#pragma unroll
    for (int r = 0; r < 8; ++r) acc[q][r] = 0.f;

  for (int k0 = 0; k0 < K; k0 += 32) {
#pragma unroll
    for (int it = 0; it < 4; ++it) {
      int idx = tid + it * 256;
      int row = idx >> 3, c4 = idx & 7;
      const float4 f = *(const float4*)&A[(long)(m0 + row) * K + k0 + c4 * 4];
      As[c4 * 4 + 0][row] = f.x;
      As[c4 * 4 + 1][row] = f.y;
      As[c4 * 4 + 2][row] = f.z;
      As[c4 * 4 + 3][row] = f.w;
    }
#pragma unroll
    for (int it = 0; it < 4; ++it) {
      int idx = tid + it * 256;
      int row = idx >> 5, c4 = idx & 31;
      int col = n0 + c4 * 4;
      float4 f;
      if (col + 3 < N) {
        f = *(const float4*)&Bg[(long)(k0 + row) * N + col];
      } else {
        f.x = (col + 0 < N) ? Bg[(long)(k0 + row) * N + col + 0] : 0.f;
        f.y = (col + 1 < N) ? Bg[(long)(k0 + row) * N + col + 1] : 0.f;
        f.z = (col + 2 < N) ? Bg[(long)(k0 + row) * N + col + 2] : 0.f;
        f.w = (col + 3 < N) ? Bg[(long)(k0 + row) * N + col + 3] : 0.f;
      }
      *(float4*)&Bs[row][c4 * 4] = f;
    }
    __syncthreads();
#pragma unroll
    for (int kk = 0; kk < 32; ++kk) {
      const float4 a0 = *(const float4*)&As[kk][ty * 8];
      const float4 a1 = *(const float4*)&As[kk][ty * 8 + 4];
      const float4 b0 = *(const float4*)&Bs[kk][tx * 8];
      const float4 b1 = *(const float4*)&Bs[kk][tx * 8 + 4];
      const float am[8] = {a0.x, a0.y, a0.z, a0.w, a1.x, a1.y, a1.z, a1.w};
      const float bn[8] = {b0.x, b0.y, b0.z, b0.w, b1.x, b1.y, b1.z, b1.w};
#pragma unroll
      for (int q = 0; q < 8; ++q)
#pragma unroll
        for (int r = 0; r < 8; ++r) acc[q][r] += am[q] * bn[r];
    }
    __syncthreads();
  }

#pragma unroll
  for (int q = 0; q < 8; ++q) {
    int m = m0 + ty * 8 + q;
    float bv = bias ? bias[m] : 0.f;
#pragma unroll
    for (int half = 0; half < 8; half += 4) {
      int col = n0 + tx * 8 + half;
#pragma unroll
      for (int rr = 0; rr < 4; ++rr)
        if (col + rr < N) C[(long)m * N + col + rr] = acc[q][half + rr] + bv;
    }
  }
}

// -------- LayerNorm + exact GELU on window tokens ----------------------------------
__global__ __launch_bounds__(256) void k_ln_gelu(const float* __restrict__ OUT1,
                                                 const float* __restrict__ lnw,
                                                 const float* __restrict__ lnb,
                                                 float* __restrict__ G) {
  const int tid = threadIdx.x;
  const int r = blockIdx.x * 8 + (tid >> 5);
  const int l = tid & 31;
  const int bb = r >> 10, hh = (r >> 6) & 15, wp = r & 63;
  float v = OUT1[((long)((bb * 64 + wp) * 16 + hh)) * 1600 + l];
  float s = v, s2 = v * v;
#pragma unroll
  for (int o = 16; o >= 1; o >>= 1) {
    s += __shfl_xor(s, o, 32);
    s2 += __shfl_xor(s2, o, 32);
  }
  float mu = s * (1.f / 32.f);
  float var = s2 * (1.f / 32.f) - mu * mu;
  float xn = (v - mu) * rsqrtf(var + 1e-5f) * lnw[l] + lnb[l];
  float g = 0.5f * xn * (1.f + erff(xn * 0.70710678118654752f));
  G[((long)(bb * 512 + hh * 32 + l)) * 64 + wp] = g;
}

// -------- stage-2 attention + aggregation ------------------------------------------
__global__ __launch_bounds__(256) void k_attn2_agg(const float* __restrict__ QK,
                                                   const float* __restrict__ OUT1,
                                                   float* __restrict__ AGG) {
  const int bh = blockIdx.x;
  const int bb = bh >> 4, hh = bh & 15;
  const int tid = threadIdx.x;
  __shared__ float wqs[64 * 33], wks[64 * 33];
  __shared__ float sd[64 * 65];
  __shared__ __align__(16) float pt[64 * 68];
  __shared__ float smx[64], ssum[64];

  for (int t = tid; t < 2048; t += 256) {
    int dd = t >> 6, i = t & 63;
    wqs[i * 33 + dd] = QK[((long)(bb * 1024 + hh * 64 + dd)) * 64 + i] * SCALE_D;
    wks[i * 33 + dd] = QK[((long)(bb * 1024 + hh * 64 + 32 + dd)) * 64 + i];
  }
  __syncthreads();
  for (int t = tid; t < 4096; t += 256) {
    int i = t >> 6, j = t & 63;
    float s = 0.f;
#pragma unroll
    for (int dd = 0; dd < 32; ++dd) s += wqs[i * 33 + dd] * wks[j * 33 + dd];
    sd[i * 65 + j] = s;
  }
  __syncthreads();
  if (tid < 64) {
    float mx = -1e30f;
    for (int j = 0; j < 64; ++j) mx = fmaxf(mx, sd[tid * 65 + j]);
    float sm = 0.f;
    for (int j = 0; j < 64; ++j) sm += expf(sd[tid * 65 + j] - mx);
    smx[tid] = mx;
    ssum[tid] = 1.f / sm;
  }
  __syncthreads();
  for (int t = tid; t < 4096; t += 256) {
    int i = t >> 6, j = t & 63;
    pt[j * 68 + i] = expf(sd[i * 65 + j] - smx[i]) * ssum[i];
  }
  __syncthreads();

  const int jd = blockIdx.y * 256 + tid;
  const bool act = jd < 1568;
  float acc[64];
#pragma unroll
  for (int i = 0; i < 64; ++i) acc[i] = 0.f;
  for (int wp = 0; wp < 64; ++wp) {
    float pv = act ? OUT1[((long)((bb * 64 + wp) * 16 + hh)) * 1600 + 32 + jd] : 0.f;
#pragma unroll
    for (int ii = 0; ii < 64; ii += 4) {
      const float4 p = *(const float4*)&pt[wp * 68 + ii];
      acc[ii + 0] += p.x * pv;
      acc[ii + 1] += p.y * pv;
      acc[ii + 2] += p.z * pv;
      acc[ii + 3] += p.w * pv;
    }
  }
  if (act) {
    long base = (long)bh * 64 * 1568 + jd;
#pragma unroll
    for (int i = 0; i < 64; ++i) AGG[base + (long)i * 1568] = acc[i];
  }
}

// -------- AGG -> FMAP^T hi/lo bf16 [16][3200][512] ---------------------------------
__global__ __launch_bounds__(256) void k_fmap_T(const float* __restrict__ AGG,
                                                unsigned short* __restrict__ Thi,
                                                unsigned short* __restrict__ Tlo) {
  const int wp = blockIdx.x, bb = blockIdx.y;
  const int Xw = wp >> 3, Yw = wp & 7;
  const int c = threadIdx.x * 2;
  const int hh = c >> 5, d0 = c & 31;
  const long abase = ((long)(bb * 16 + hh) * 64 + wp) * 1568;
  for (int j = 0; j < 49; ++j) {
    float v0 = AGG[abase + j * 32 + d0];
    float v1 = AGG[abase + j * 32 + d0 + 1];
    int hw = (Xw * 7 + j / 7) * 56 + Yw * 7 + j % 7;
    long t = ((long)bb * 3200 + hw) * 512 + c;
    unsigned short h0 = f2bf(v0), h1 = f2bf(v1);
    Thi[t] = h0;
    Thi[t + 1] = h1;
    Tlo[t] = f2bf(v0 - bf2f(h0));
    Tlo[t + 1] = f2bf(v1 - bf2f(h1));
  }
}

__global__ __launch_bounds__(256) void k_padzero(unsigned short* __restrict__ Thi,
                                                 unsigned short* __restrict__ Tlo) {
  const int bb = blockIdx.x;
  for (int e = threadIdx.x; e < 32768; e += 256) {
    long idx = ((long)bb * 3200 + 3136) * 512 + e;
    Thi[idx] = 0;
    Tlo[idx] = 0;
  }
}

// ---------------- launch ----------------
extern "C" void kernel_launch(void* const* d_in, const int* in_sizes, int n_in,
                              void* d_out, int out_size, void* d_ws, size_t ws_size,
                              hipStream_t stream) {
  const float* x     = (const float*)d_in[0];
  const float* w_qkv = (const float*)d_in[1];
  const float* wt    = (const float*)d_in[2];
  const float* lnw   = (const float*)d_in[3];
  const float* lnb   = (const float*)d_in[4];
  const float* w_qk  = (const float*)d_in[5];
  const float* b_qk  = (const float*)d_in[6];
  const float* w_out = (const float*)d_in[7];
  const float* b_out = (const float*)d_in[8];
  float* out = (float*)d_out;
  float* ws  = (float*)d_ws;

  // ws: OUT1 [26,214,400 f32] then AUX [1,572,864 f32] — total 111.1 MB (proven)
  float* OUT1 = ws;
  float* AUX  = ws + 26214400L;
  unsigned short* Whi = (unsigned short*)AUX;            // 786,432 (QKV phase)
  unsigned short* Wlo = Whi + 786432L;
  float* G  = AUX;                                       // 524,288 (after QKV phase)
  float* QK = AUX + 524288L;                             // 1,048,576
  unsigned short* WOhi = (unsigned short*)AUX;           // 262,144 (final phase, G dead)
  unsigned short* WOlo = WOhi + 262144L;
  unsigned short* FThi = (unsigned short*)ws;            // 26,214,400 (OUT1 dead)
  unsigned short* FTlo = FThi + 26214400L;

  // d_out as scratch: XcT chunk hi/lo (6.55M ushort each) + QKV chunk f32 (9.83M)
  unsigned short* XThi = (unsigned short*)d_out;         // 3,276,800
  unsigned short* XTlo = XThi + 3276800L;
  float* QKVc = out + 3276800L;                          // 9,830,400 f32, ends 13.1M < 25.69M
  float* AGG  = out;                                     // full d_out, after QKV phase

  // 1. split w_qkv -> bf16 hi/lo
  k_split<<<3072, 256, 0, stream>>>(w_qkv, Whi, Wlo, 786432);
  // 2. per 2-image chunk: gather XcT, QKV MFMA GEMM, stage-1 attention
  for (int c = 0; c < 8; ++c) {
    k_build_xcT<<<dim3(8, 57, 2), 256, 0, stream>>>(x, wt, XThi, XTlo, c * 2);
    k_gemm_mfma<<<dim3(50, 12, 1), 256, 0, stream>>>(Whi, Wlo, XThi, XTlo, QKVc,
                                                     nullptr, 6400, 0, 0);
    k_attn1<<<2048, 256, 0, stream>>>(QKVc, OUT1, c * 128);
  }
  // 3. LN + GELU -> G
  k_ln_gelu<<<2048, 256, 0, stream>>>(OUT1, lnw, lnb, G);
  // 4. qk = w_qk @ G + b_qk (f32, small)
  k_gemm<<<dim3(1, 8, 16), 256, 0, stream>>>(w_qk, G, QK, b_qk,
                                             1024, 64, 512, 512L * 64, 1024L * 64);
  // 5. split w_out (into G region, dead now)
  k_split<<<1024, 256, 0, stream>>>(w_out, WOhi, WOlo, 262144);
  // 6. stage-2 attention + aggregation -> AGG (d_out)
  k_attn2_agg<<<dim3(256, 7, 1), 256, 0, stream>>>(QK, OUT1, AGG);
  // 7. AGG -> FMAP^T hi/lo (overwrites OUT1 region) + zero pad rows
  k_fmap_T<<<dim3(64, 16), 256, 0, stream>>>(AGG, FThi, FTlo);
  k_padzero<<<16, 256, 0, stream>>>(FThi, FTlo);
  // 8. out = w_out @ FMAP + b_out (split-bf16 MFMA, batched over 16 images)
  k_gemm_mfma<<<dim3(25, 4, 16), 256, 0, stream>>>(WOhi, WOlo, FThi, FTlo, out,
                                                   b_out, 3136, 3200, 512L * 3136);
}

// Round 5
// 994.008 us; speedup vs baseline: 5.2529x; 1.2417x over previous
//
#include <hip/hip_runtime.h>
#include <math.h>

// b=16, C=512, H=W=56, wsz=7, X=Y=8, nw=64/img, n=49, tokens=50, heads=16, dhead=32
#define SCALE_D 0.17677669529663687f  // 32^-0.5

typedef __attribute__((ext_vector_type(8))) short short8;
typedef __attribute__((ext_vector_type(4))) float f32x4;

__device__ __forceinline__ unsigned short f2bf(float f) {
  unsigned u = __builtin_bit_cast(unsigned, f);
  unsigned r = u + 0x7FFF + ((u >> 16) & 1);
  return (unsigned short)(r >> 16);
}
__device__ __forceinline__ float bf2f(unsigned short h) {
  unsigned u = ((unsigned)h) << 16;
  return __builtin_bit_cast(float, u);
}
__device__ __forceinline__ void gload16(const void* g, void* l) {
  __builtin_amdgcn_global_load_lds((const __attribute__((address_space(1))) unsigned int*)g,
                                   (__attribute__((address_space(3))) unsigned int*)l,
                                   16, 0, 0);
}

// -------- split f32 -> bf16 hi/lo planes ------------------------------------------
__global__ __launch_bounds__(256) void k_split(const float* __restrict__ src,
                                               unsigned short* __restrict__ hi,
                                               unsigned short* __restrict__ lo, int n) {
  int i = blockIdx.x * 256 + threadIdx.x;
  if (i < n) {
    float v = src[i];
    unsigned short h = f2bf(v);
    hi[i] = h;
    lo[i] = f2bf(v - bf2f(h));
  }
}

// -------- gather Xc^T chunk (2 images) as bf16 hi/lo [6400][512] -------------------
__global__ __launch_bounds__(256) void k_build_xcT(const float* __restrict__ x,
                                                   const float* __restrict__ wtok,
                                                   unsigned short* __restrict__ Thi,
                                                   unsigned short* __restrict__ Tlo,
                                                   int bb0) {
  const int cblk = blockIdx.x;   // 0..7
  const int h    = blockIdx.y;   // 0..55 pixels, 56 = token-0 pass
  const int bbL  = blockIdx.z;   // 0..1
  const int bb   = bb0 + bbL;
  const int tid  = threadIdx.x;
  const int c0   = cblk * 64;
  if (h == 56) {
    for (int e = tid; e < 4096; e += 256) {
      int wl = e >> 6, cl = e & 63;
      float v = wtok[c0 + cl];
      unsigned short hv = f2bf(v);
      long idx = ((long)(bbL * 64 + wl) * 50) * 512 + c0 + cl;
      Thi[idx] = hv;
      Tlo[idx] = f2bf(v - bf2f(hv));
    }
    return;
  }
  __shared__ unsigned short shi[64][57], slo[64][57];
  const int Xw = h / 7, r7 = h % 7;
  for (int e = tid; e < 3584; e += 256) {
    int cl = e / 56, w = e - cl * 56;
    float v = x[((long)(bb * 512 + c0 + cl) * 56 + h) * 56 + w];
    unsigned short hv = f2bf(v);
    shi[cl][w] = hv;
    slo[cl][w] = f2bf(v - bf2f(hv));
  }
  __syncthreads();
  for (int e = tid; e < 3584; e += 256) {
    int row = e >> 6, cl = e & 63;       // row = Yw*7+c7
    int Yw = row / 7, c7 = row - Yw * 7;
    long trow = (long)(bbL * 64 + Xw * 8 + Yw) * 50 + 1 + r7 * 7 + c7;
    Thi[trow * 512 + c0 + cl] = shi[cl][row];
    Tlo[trow * 512 + c0 + cl] = slo[cl][row];
  }
}

// -------- split-bf16 MFMA GEMM: C = A(f32~hi+lo) * B^T(rows=[n][k]) ---------------
__global__ __launch_bounds__(256, 2) void k_gemm_mfma(
    const unsigned short* __restrict__ Ahi, const unsigned short* __restrict__ Alo,
    const unsigned short* __restrict__ Bhi, const unsigned short* __restrict__ Blo,
    float* __restrict__ C, const float* __restrict__ bias,
    int NC, int brow_stride, long c_stride) {
  __shared__ unsigned short lds[4][128][32];
  const int tid = threadIdx.x;
  const int wv = tid >> 6, lane = tid & 63;
  const int m0 = blockIdx.y * 128, n0 = blockIdx.x * 128;
  const long brow0 = (long)blockIdx.z * brow_stride + n0;
  C += (long)blockIdx.z * c_stride;

  const int wr = wv >> 1, wc = wv & 1;
  const int lr = lane & 15, kb = lane >> 4;
  const int srow = lane >> 2, sju = lane & 3;

  f32x4 acc[4][4];
#pragma unroll
  for (int i = 0; i < 4; ++i)
#pragma unroll
    for (int j = 0; j < 4; ++j) {
      f32x4 z = {0.f, 0.f, 0.f, 0.f};
      acc[i][j] = z;
    }

  for (int k0 = 0; k0 < 512; k0 += 32) {
#pragma unroll
    for (int it = 0; it < 2; ++it) {
      const int rloc = (wv * 2 + it) * 16;
      const int r = rloc + srow;
      const long ga = (long)(m0 + r) * 512 + k0 + sju * 8;
      gload16(Ahi + ga, &lds[0][rloc][0]);
      gload16(Alo + ga, &lds[1][rloc][0]);
      const long gb = (brow0 + r) * 512 + k0 + sju * 8;
      gload16(Bhi + gb, &lds[2][rloc][0]);
      gload16(Blo + gb, &lds[3][rloc][0]);
    }
    __syncthreads();
    short8 ah[4], al[4], bh[4], bl[4];
#pragma unroll
    for (int f = 0; f < 4; ++f) {
      int ra = wr * 64 + f * 16 + lr;
      ah[f] = *(const short8*)&lds[0][ra][kb * 8];
      al[f] = *(const short8*)&lds[1][ra][kb * 8];
      int rb = wc * 64 + f * 16 + lr;
      bh[f] = *(const short8*)&lds[2][rb][kb * 8];
      bl[f] = *(const short8*)&lds[3][rb][kb * 8];
    }
#pragma unroll
    for (int i = 0; i < 4; ++i)
#pragma unroll
      for (int j = 0; j < 4; ++j) {
        acc[i][j] = __builtin_amdgcn_mfma_f32_16x16x32_bf16(ah[i], bh[j], acc[i][j], 0, 0, 0);
        acc[i][j] = __builtin_amdgcn_mfma_f32_16x16x32_bf16(ah[i], bl[j], acc[i][j], 0, 0, 0);
        acc[i][j] = __builtin_amdgcn_mfma_f32_16x16x32_bf16(al[i], bh[j], acc[i][j], 0, 0, 0);
      }
    __syncthreads();
  }

#pragma unroll
  for (int i = 0; i < 4; ++i)
#pragma unroll
    for (int nf = 0; nf < 4; ++nf) {
      int col = n0 + wc * 64 + nf * 16 + lr;
      if (col < NC) {
#pragma unroll
        for (int j4 = 0; j4 < 4; ++j4) {
          int row = m0 + wr * 64 + i * 16 + kb * 4 + j4;
          float bv = bias ? bias[row] : 0.f;
          C[(long)row * NC + col] = acc[i][nf][j4] + bv;
        }
      }
    }
}

// -------- stage-1 attention, MFMA, one wave per (window, head) ---------------------
// QKV layout: [feature 1536][token 6400] f32; window wl has tokens wl*50..+50.
__global__ __launch_bounds__(256) void k_attn1_mfma(const float* __restrict__ QKV,
                                                    float* __restrict__ OUT1, int w0) {
  __shared__ unsigned short P[4][16][72];  // per-wave P relayout buffer
  const int tid = threadIdx.x;
  const int wv = tid >> 6, lane = tid & 63;
  const int idx = blockIdx.x * 4 + wv;     // wl*16 + h
  const int wl = idx >> 4, h = idx & 15;
  const int lr = lane & 15, kb = lane >> 4;
  const long tb = (long)wl * 50;

  // K fragments (B-operand for scores): n=j=jt*16+lr, k=dd=kb*8+e; split hi/lo
  short8 kh[4], kl[4];
#pragma unroll
  for (int jt = 0; jt < 4; ++jt) {
    float f[8];
#pragma unroll
    for (int e = 0; e < 8; ++e)
      f[e] = QKV[(long)(512 + h * 32 + kb * 8 + e) * 6400 + tb + jt * 16 + lr];
#pragma unroll
    for (int e = 0; e < 8; ++e) {
      unsigned short hh = f2bf(f[e]);
      kh[jt][e] = (short)hh;
      kl[jt][e] = (short)f2bf(f[e] - bf2f(hh));
    }
  }
  // V fragments (B-operand for PV): n=dd=ddt*16+lr, k=j=ks*32+kb*8+e; zero j>=50
  short8 vh[2][2], vl[2][2];
#pragma unroll
  for (int ddt = 0; ddt < 2; ++ddt)
#pragma unroll
    for (int ks = 0; ks < 2; ++ks) {
      const long vb = (long)(1024 + h * 32 + ddt * 16 + lr) * 6400 + tb + ks * 32 + kb * 8;
      float f[8];
#pragma unroll
      for (int e = 0; e < 8; ++e) {
        int j = ks * 32 + kb * 8 + e;
        f[e] = (j < 50) ? QKV[vb + e] : 0.f;
      }
#pragma unroll
      for (int e = 0; e < 8; ++e) {
        unsigned short hh = f2bf(f[e]);
        vh[ddt][ks][e] = (short)hh;
        vl[ddt][ks][e] = (short)f2bf(f[e] - bf2f(hh));
      }
    }

  const long ob = (long)((w0 + wl) * 16 + h) * 1600;

  for (int it = 0; it < 4; ++it) {
    // Q fragment (A-operand): m=i=it*16+lr, k=dd=kb*8+e; scale folded in
    short8 qh, ql;
    {
      float f[8];
#pragma unroll
      for (int e = 0; e < 8; ++e)
        f[e] = QKV[(long)(h * 32 + kb * 8 + e) * 6400 + tb + it * 16 + lr] * SCALE_D;
#pragma unroll
      for (int e = 0; e < 8; ++e) {
        unsigned short hh = f2bf(f[e]);
        qh[e] = (short)hh;
        ql[e] = (short)f2bf(f[e] - bf2f(hh));
      }
    }
    // scores: D[i][j], lane holds j=jt*16+lr (col), i=it*16+kb*4+r (row)
    f32x4 s[4];
#pragma unroll
    for (int jt = 0; jt < 4; ++jt) {
      f32x4 z = {0.f, 0.f, 0.f, 0.f};
      s[jt] = z;
      s[jt] = __builtin_amdgcn_mfma_f32_16x16x32_bf16(qh, kh[jt], s[jt], 0, 0, 0);
      s[jt] = __builtin_amdgcn_mfma_f32_16x16x32_bf16(qh, kl[jt], s[jt], 0, 0, 0);
      s[jt] = __builtin_amdgcn_mfma_f32_16x16x32_bf16(ql, kh[jt], s[jt], 0, 0, 0);
    }
    // mask j>=50 (jt=3, lr>=2)
    if (lr >= 2) {
#pragma unroll
      for (int r = 0; r < 4; ++r) s[3][r] = -1e30f;
    }
    // softmax per row i (reduce over jt in-lane + 16 j-lanes via shfl)
    float ex[4][4], rinv[4];
#pragma unroll
    for (int r = 0; r < 4; ++r) {
      float m = fmaxf(fmaxf(s[0][r], s[1][r]), fmaxf(s[2][r], s[3][r]));
      m = fmaxf(m, __shfl_xor(m, 1));
      m = fmaxf(m, __shfl_xor(m, 2));
      m = fmaxf(m, __shfl_xor(m, 4));
      m = fmaxf(m, __shfl_xor(m, 8));
      float sm = 0.f;
#pragma unroll
      for (int jt = 0; jt < 4; ++jt) {
        ex[jt][r] = __expf(s[jt][r] - m);
        sm += ex[jt][r];
      }
      sm += __shfl_xor(sm, 1);
      sm += __shfl_xor(sm, 2);
      sm += __shfl_xor(sm, 4);
      sm += __shfl_xor(sm, 8);
      rinv[r] = 1.f / sm;
    }
    // write P (bf16) to LDS: P[i_loc][j]
#pragma unroll
    for (int jt = 0; jt < 4; ++jt)
#pragma unroll
      for (int r = 0; r < 4; ++r)
        P[wv][kb * 4 + r][jt * 16 + lr] = f2bf(ex[jt][r] * rinv[r]);
    // PV: A=P (m=i=lr, k=j), B=V; out[i][dd]
    short8 pa0 = *(const short8*)&P[wv][lr][kb * 8];
    short8 pa1 = *(const short8*)&P[wv][lr][32 + kb * 8];
    f32x4 o[2];
#pragma unroll
    for (int ddt = 0; ddt < 2; ++ddt) {
      f32x4 z = {0.f, 0.f, 0.f, 0.f};
      o[ddt] = z;
      o[ddt] = __builtin_amdgcn_mfma_f32_16x16x32_bf16(pa0, vh[ddt][0], o[ddt], 0, 0, 0);
      o[ddt] = __builtin_amdgcn_mfma_f32_16x16x32_bf16(pa0, vl[ddt][0], o[ddt], 0, 0, 0);
      o[ddt] = __builtin_amdgcn_mfma_f32_16x16x32_bf16(pa1, vh[ddt][1], o[ddt], 0, 0, 0);
      o[ddt] = __builtin_amdgcn_mfma_f32_16x16x32_bf16(pa1, vl[ddt][1], o[ddt], 0, 0, 0);
    }
    // store rows i = it*16 + kb*4 + r, cols dd = ddt*16 + lr
#pragma unroll
    for (int ddt = 0; ddt < 2; ++ddt)
#pragma unroll
      for (int r = 0; r < 4; ++r) {
        int i = it * 16 + kb * 4 + r;
        if (i < 50) OUT1[ob + i * 32 + ddt * 16 + lr] = o[ddt][r];
      }
  }
}

// -------- f32 GEMM (kept for the small qk projection) ------------------------------
__global__ __launch_bounds__(256) void k_gemm(const float* __restrict__ A,
                                              const float* __restrict__ Bg,
                                              float* __restrict__ C,
                                              const float* __restrict__ bias,
                                              int M, int N, int K, long sB, long sC) {
  Bg += (long)blockIdx.z * sB;
  C  += (long)blockIdx.z * sC;
  __shared__ __align__(16) float As[32][132];
  __shared__ __align__(16) float Bs[32][132];
  const int tid = threadIdx.x;
  const int tx = tid & 15, ty = tid >> 4;
  const int m0 = blockIdx.y * 128, n0 = blockIdx.x * 128;

  float acc[8][8];
#pragma unroll
  for (int q = 0; q < 8; ++q)
#pragma unroll
    for (int r = 0; r < 8; ++r) acc[q][r] = 0.f;

  for (int k0 = 0; k0 < K; k0 += 32) {
#pragma unroll
    for (int it = 0; it < 4; ++it) {
      int idx = tid + it * 256;
      int row = idx >> 3, c4 = idx & 7;
      const float4 f = *(const float4*)&A[(long)(m0 + row) * K + k0 + c4 * 4];
      As[c4 * 4 + 0][row] = f.x;
      As[c4 * 4 + 1][row] = f.y;
      As[c4 * 4 + 2][row] = f.z;
      As[c4 * 4 + 3][row] = f.w;
    }
#pragma unroll
    for (int it = 0; it < 4; ++it) {
      int idx = tid + it * 256;
      int row = idx >> 5, c4 = idx & 31;
      int col = n0 + c4 * 4;
      float4 f;
      if (col + 3 < N) {
        f = *(const float4*)&Bg[(long)(k0 + row) * N + col];
      } else {
        f.x = (col + 0 < N) ? Bg[(long)(k0 + row) * N + col + 0] : 0.f;
        f.y = (col + 1 < N) ? Bg[(long)(k0 + row) * N + col + 1] : 0.f;
        f.z = (col + 2 < N) ? Bg[(long)(k0 + row) * N + col + 2] : 0.f;
        f.w = (col + 3 < N) ? Bg[(long)(k0 + row) * N + col + 3] : 0.f;
      }
      *(float4*)&Bs[row][c4 * 4] = f;
    }
    __syncthreads();
#pragma unroll
    for (int kk = 0; kk < 32; ++kk) {
      const float4 a0 = *(const float4*)&As[kk][ty * 8];
      const float4 a1 = *(const float4*)&As[kk][ty * 8 + 4];
      const float4 b0 = *(const float4*)&Bs[kk][tx * 8];
      const float4 b1 = *(const float4*)&Bs[kk][tx * 8 + 4];
      const float am[8] = {a0.x, a0.y, a0.z, a0.w, a1.x, a1.y, a1.z, a1.w};
      const float bn[8] = {b0.x, b0.y, b0.z, b0.w, b1.x, b1.y, b1.z, b1.w};
#pragma unroll
      for (int q = 0; q < 8; ++q)
#pragma unroll
        for (int r = 0; r < 8; ++r) acc[q][r] += am[q] * bn[r];
    }
    __syncthreads();
  }

#pragma unroll
  for (int q = 0; q < 8; ++q) {
    int m = m0 + ty * 8 + q;
    float bv = bias ? bias[m] : 0.f;
#pragma unroll
    for (int half = 0; half < 8; half += 4) {
      int col = n0 + tx * 8 + half;
#pragma unroll
      for (int rr = 0; rr < 4; ++rr)
        if (col + rr < N) C[(long)m * N + col + rr] = acc[q][half + rr] + bv;
    }
  }
}

// -------- LayerNorm + exact GELU on window tokens ----------------------------------
__global__ __launch_bounds__(256) void k_ln_gelu(const float* __restrict__ OUT1,
                                                 const float* __restrict__ lnw,
                                                 const float* __restrict__ lnb,
                                                 float* __restrict__ G) {
  const int tid = threadIdx.x;
  const int r = blockIdx.x * 8 + (tid >> 5);
  const int l = tid & 31;
  const int bb = r >> 10, hh = (r >> 6) & 15, wp = r & 63;
  float v = OUT1[((long)((bb * 64 + wp) * 16 + hh)) * 1600 + l];
  float s = v, s2 = v * v;
#pragma unroll
  for (int o = 16; o >= 1; o >>= 1) {
    s += __shfl_xor(s, o, 32);
    s2 += __shfl_xor(s2, o, 32);
  }
  float mu = s * (1.f / 32.f);
  float var = s2 * (1.f / 32.f) - mu * mu;
  float xn = (v - mu) * rsqrtf(var + 1e-5f) * lnw[l] + lnb[l];
  float g = 0.5f * xn * (1.f + erff(xn * 0.70710678118654752f));
  G[((long)(bb * 512 + hh * 32 + l)) * 64 + wp] = g;
}

// -------- stage-2 attention + aggregation (register-blocked agg) -------------------
__global__ __launch_bounds__(256) void k_attn2_agg(const float* __restrict__ QK,
                                                   const float* __restrict__ OUT1,
                                                   float* __restrict__ AGG) {
  const int bh = blockIdx.x;
  const int bb = bh >> 4, hh = bh & 15;
  const int tid = threadIdx.x;
  __shared__ float wqs[64 * 33], wks[64 * 33];
  __shared__ float sd[64 * 65];
  __shared__ __align__(16) float pt[64 * 68];
  __shared__ float smx[64], ssum[64];

  for (int t = tid; t < 2048; t += 256) {
    int dd = t >> 6, i = t & 63;
    wqs[i * 33 + dd] = QK[((long)(bb * 1024 + hh * 64 + dd)) * 64 + i] * SCALE_D;
    wks[i * 33 + dd] = QK[((long)(bb * 1024 + hh * 64 + 32 + dd)) * 64 + i];
  }
  __syncthreads();
  for (int t = tid; t < 4096; t += 256) {
    int i = t >> 6, j = t & 63;
    float s = 0.f;
#pragma unroll
    for (int dd = 0; dd < 32; ++dd) s += wqs[i * 33 + dd] * wks[j * 33 + dd];
    sd[i * 65 + j] = s;
  }
  __syncthreads();
  if (tid < 64) {
    float mx = -1e30f;
    for (int j = 0; j < 64; ++j) mx = fmaxf(mx, sd[tid * 65 + j]);
    float sm = 0.f;
    for (int j = 0; j < 64; ++j) sm += expf(sd[tid * 65 + j] - mx);
    smx[tid] = mx;
    ssum[tid] = 1.f / sm;
  }
  __syncthreads();
  for (int t = tid; t < 4096; t += 256) {
    int i = t >> 6, j = t & 63;
    pt[j * 68 + i] = expf(sd[i * 65 + j] - smx[i]) * ssum[i];
  }
  __syncthreads();

  // agg: thread = (ih half of i, 4 consecutive jd)
  const int ih = tid >> 7, jl = tid & 127;
  const int jd = blockIdx.y * 512 + jl * 4;
  const bool act = jd < 1568;
  float4 acc[32];
#pragma unroll
  for (int i = 0; i < 32; ++i) acc[i] = make_float4(0.f, 0.f, 0.f, 0.f);
  for (int wp = 0; wp < 64; ++wp) {
    float4 pv = make_float4(0.f, 0.f, 0.f, 0.f);
    if (act) pv = *(const float4*)&OUT1[((long)((bb * 64 + wp) * 16 + hh)) * 1600 + 32 + jd];
#pragma unroll
    for (int ii = 0; ii < 32; ii += 4) {
      const float4 p = *(const float4*)&pt[wp * 68 + ih * 32 + ii];
      acc[ii + 0].x += p.x * pv.x; acc[ii + 0].y += p.x * pv.y;
      acc[ii + 0].z += p.x * pv.z; acc[ii + 0].w += p.x * pv.w;
      acc[ii + 1].x += p.y * pv.x; acc[ii + 1].y += p.y * pv.y;
      acc[ii + 1].z += p.y * pv.z; acc[ii + 1].w += p.y * pv.w;
      acc[ii + 2].x += p.z * pv.x; acc[ii + 2].y += p.z * pv.y;
      acc[ii + 2].z += p.z * pv.z; acc[ii + 2].w += p.z * pv.w;
      acc[ii + 3].x += p.w * pv.x; acc[ii + 3].y += p.w * pv.y;
      acc[ii + 3].z += p.w * pv.z; acc[ii + 3].w += p.w * pv.w;
    }
  }
  if (act) {
    const long base = (long)bh * 100352 + jd;
#pragma unroll
    for (int i = 0; i < 32; ++i)
      *(float4*)&AGG[base + (long)(ih * 32 + i) * 1568] = acc[i];
  }
}

// -------- AGG -> FMAP^T hi/lo bf16 [16][3200][512] ---------------------------------
__global__ __launch_bounds__(256) void k_fmap_T(const float* __restrict__ AGG,
                                                unsigned short* __restrict__ Thi,
                                                unsigned short* __restrict__ Tlo) {
  const int wp = blockIdx.x, bb = blockIdx.y;
  const int Xw = wp >> 3, Yw = wp & 7;
  const int c = threadIdx.x * 2;
  const int hh = c >> 5, d0 = c & 31;
  const long abase = ((long)(bb * 16 + hh) * 64 + wp) * 1568;
  for (int j = 0; j < 49; ++j) {
    float v0 = AGG[abase + j * 32 + d0];
    float v1 = AGG[abase + j * 32 + d0 + 1];
    int hw = (Xw * 7 + j / 7) * 56 + Yw * 7 + j % 7;
    long t = ((long)bb * 3200 + hw) * 512 + c;
    unsigned short h0 = f2bf(v0), h1 = f2bf(v1);
    Thi[t] = h0;
    Thi[t + 1] = h1;
    Tlo[t] = f2bf(v0 - bf2f(h0));
    Tlo[t + 1] = f2bf(v1 - bf2f(h1));
  }
}

__global__ __launch_bounds__(256) void k_padzero(unsigned short* __restrict__ Thi,
                                                 unsigned short* __restrict__ Tlo) {
  const int bb = blockIdx.x;
  for (int e = threadIdx.x; e < 32768; e += 256) {
    long idx = ((long)bb * 3200 + 3136) * 512 + e;
    Thi[idx] = 0;
    Tlo[idx] = 0;
  }
}

// ---------------- launch ----------------
extern "C" void kernel_launch(void* const* d_in, const int* in_sizes, int n_in,
                              void* d_out, int out_size, void* d_ws, size_t ws_size,
                              hipStream_t stream) {
  const float* x     = (const float*)d_in[0];
  const float* w_qkv = (const float*)d_in[1];
  const float* wt    = (const float*)d_in[2];
  const float* lnw   = (const float*)d_in[3];
  const float* lnb   = (const float*)d_in[4];
  const float* w_qk  = (const float*)d_in[5];
  const float* b_qk  = (const float*)d_in[6];
  const float* w_out = (const float*)d_in[7];
  const float* b_out = (const float*)d_in[8];
  float* out = (float*)d_out;
  float* ws  = (float*)d_ws;

  // ws: OUT1 [26,214,400 f32] then AUX [1,572,864 f32] — 111.1 MB total (proven)
  float* OUT1 = ws;
  float* AUX  = ws + 26214400L;
  unsigned short* Whi = (unsigned short*)AUX;            // QKV phase
  unsigned short* Wlo = Whi + 786432L;
  float* G  = AUX;                                       // after QKV phase
  float* QK = AUX + 524288L;
  unsigned short* WOhi = (unsigned short*)AUX;           // final phase (G dead)
  unsigned short* WOlo = WOhi + 262144L;
  unsigned short* FThi = (unsigned short*)ws;            // OUT1 dead
  unsigned short* FTlo = FThi + 26214400L;

  // d_out as scratch
  unsigned short* XThi = (unsigned short*)d_out;         // 3,276,800
  unsigned short* XTlo = XThi + 3276800L;
  float* QKVc = out + 3276800L;                          // 9,830,400 f32 (ends 13.1M)
  float* AGG  = out;                                     // after QKV phase

  // 1. split w_qkv -> bf16 hi/lo
  k_split<<<3072, 256, 0, stream>>>(w_qkv, Whi, Wlo, 786432);
  // 2. per 2-image chunk: gather XcT, QKV MFMA GEMM, stage-1 MFMA attention
  for (int c = 0; c < 8; ++c) {
    k_build_xcT<<<dim3(8, 57, 2), 256, 0, stream>>>(x, wt, XThi, XTlo, c * 2);
    k_gemm_mfma<<<dim3(50, 12, 1), 256, 0, stream>>>(Whi, Wlo, XThi, XTlo, QKVc,
                                                     nullptr, 6400, 0, 0);
    k_attn1_mfma<<<512, 256, 0, stream>>>(QKVc, OUT1, c * 128);
  }
  // 3. LN + GELU -> G
  k_ln_gelu<<<2048, 256, 0, stream>>>(OUT1, lnw, lnb, G);
  // 4. qk = w_qk @ G + b_qk
  k_gemm<<<dim3(1, 8, 16), 256, 0, stream>>>(w_qk, G, QK, b_qk,
                                             1024, 64, 512, 512L * 64, 1024L * 64);
  // 5. split w_out (G region dead)
  k_split<<<1024, 256, 0, stream>>>(w_out, WOhi, WOlo, 262144);
  // 6. stage-2 attention + aggregation -> AGG (d_out)
  k_attn2_agg<<<dim3(256, 4, 1), 256, 0, stream>>>(QK, OUT1, AGG);
  // 7. AGG -> FMAP^T hi/lo + zero pad rows
  k_fmap_T<<<dim3(64, 16), 256, 0, stream>>>(AGG, FThi, FTlo);
  k_padzero<<<16, 256, 0, stream>>>(FThi, FTlo);
  // 8. out = w_out @ FMAP + b_out (split-bf16 MFMA, batched over 16 images)
  k_gemm_mfma<<<dim3(25, 4, 16), 256, 0, stream>>>(WOhi, WOlo, FThi, FTlo, out,
                                                   b_out, 3136, 3200, 512L * 3136);
}